// Round 8
// baseline (999.241 us; speedup 1.0000x reference)
//
#include <hip/hip_runtime.h>
#include <math.h>

// Sliced Wasserstein-2: for each (b,c,p): W2^2 = mean_i (sort(X@theta_p) - sort(Y@theta_p))^2
// loss = mean_{b,c} sqrt(mean_p W2^2)
//
// R24 = R23 (mask-XOR CE + branchy exch + uniform tails) with the COMPILE
// FIX: runtime keep-masks routed through __builtin_amdgcn_readfirstlane so
// clang's divergence analysis proves them uniform and the "s" (SGPR-pair)
// asm constraint is satisfiable. (R23 failed: tid-derived selects are
// "divergent" to clang -> mask landed in v[2:3] -> invalid s_xor_b64.)
//  1) mask-XOR CE: keepMin as 64-bit lane mask in SGPR pair; cross-lane CE
//     pinned to v_cmp + s_xor_b64 + v_cndmask (2 VALU + 1 SALU).
//     Compile-time masks for a=6..10; readfirstlane-uniform for a>=11.
//  2) exch-stage CEs: keepMin wave-uniform -> uniform branch, fminf OR
//     fmaxf loop = 1 VALU/CE.
//  3) wave-uniform-direction tails (a=11..15): specialized min/max nets,
//     no sign-flip XOR wrapper.
// Comparator + tie semantics identical to R22 -> absmax 0.

namespace {
constexpr int Bb = 8, Cc = 4, Nn = 32768, Pp = 50;
constexpr int T1024 = 1024;
constexpr int VPT = 32;                    // values per thread
constexpr int SLICES = Bb * Cc * Pp;       // 1600
constexpr int FLAG_WORDS = (SLICES + 31) / 32;  // 50
constexpr size_t W2_BYTES = 8192;          // w2[1600] + flags + ticket
constexpr size_t FLAGS_OFF = 6400;         // after w2 floats
constexpr size_t TICKET_OFF = 6656;
constexpr int LDS_FLOATS_FULL = Nn / 2;    // 16384 floats = 64 KB
}

// 64-bit lane mask: bit l set iff (l & M) == 0
constexpr unsigned long long km0(int M) {
  unsigned long long m = 0;
  for (int l = 0; l < 64; ++l) if ((l & M) == 0) m |= (1ull << l);
  return m;
}

// force wave-uniformity proof for SGPR constraint (HK readfirstlane pattern)
__device__ __forceinline__ unsigned long long uni64(unsigned long long x) {
  unsigned lo = (unsigned)__builtin_amdgcn_readfirstlane((int)(unsigned)x);
  unsigned hi = (unsigned)__builtin_amdgcn_readfirstlane((int)(unsigned)(x >> 32));
  return ((unsigned long long)hi << 32) | lo;
}

__device__ __forceinline__ void ce(float& a, float& b, bool up) {
  float lo = fminf(a, b);
  float hi = fmaxf(a, b);
  a = up ? lo : hi;
  b = up ? hi : lo;
}

// DPP lane move with compile-time control word.
// 0xB1 = quad_perm(1,0,3,2) = xor1; 0x4E = quad_perm(2,3,0,1) = xor2;
// 0x128 = row_ror:8 = xor8 on each 16-lane row.
template<int CTRL>
__device__ __forceinline__ float dpp_move(float x) {
  int i = __builtin_amdgcn_update_dpp(0, __float_as_int(x), CTRL, 0xF, 0xF, true);
  return __int_as_float(i);
}

// mask-XOR CE: d = ((o<v) ^ keepMin) ? v : o  (== keepMin ? min : max).
// km bit l = keepMin of lane l, held in an SGPR pair. 2 VALU + 1 SALU.
__device__ __forceinline__ void ce_mask(float& v, float o, unsigned long long km) {
  asm("v_cmp_lt_f32 vcc, %1, %0\n\t"
      "s_xor_b64 vcc, vcc, %2\n\t"
      "v_cndmask_b32 %0, %1, %0, vcc"
      : "+v"(v) : "v"(o), "s"(km) : "vcc");
}

// cross-lane CE stage with xor-mask M (M=1,2,8 via DPP; M=4,16,32 bpermute)
template<int M>
__device__ __forceinline__ void stage_m(float v[VPT], int tid,
                                        unsigned long long km) {
  if constexpr (M == 1 || M == 2 || M == 8) {
    constexpr int ctrl = (M == 1) ? 0xB1 : (M == 2) ? 0x4E : 0x128;
#pragma unroll
    for (int r = 0; r < VPT; r++) {
      float o = dpp_move<ctrl>(v[r]);
      ce_mask(v[r], o, km);
    }
  } else {
    const int addr = (((tid & 63) ^ M) << 2);
#pragma unroll
    for (int r = 0; r < VPT; r++) {
      float o = __int_as_float(
          __builtin_amdgcn_ds_bpermute(addr, __float_as_int(v[r])));
      ce_mask(v[r], o, km);
    }
  }
}

// 5-stage in-register network, sign-flip direction (lane-varying up)
__device__ __forceinline__ void tail_inreg(float v[VPT], bool up) {
  const unsigned flip = up ? 0u : 0x80000000u;
#pragma unroll
  for (int r = 0; r < VPT; r++)
    v[r] = __int_as_float(__float_as_int(v[r]) ^ flip);
#pragma unroll
  for (int j = 16; j > 0; j >>= 1) {
#pragma unroll
    for (int r = 0; r < VPT; r++) {
      if (!(r & j)) {
        float a = v[r], b = v[r | j];
        v[r] = fminf(a, b);
        v[r | j] = fmaxf(a, b);
      }
    }
  }
#pragma unroll
  for (int r = 0; r < VPT; r++)
    v[r] = __int_as_float(__float_as_int(v[r]) ^ flip);
}

// 5-stage in-register network, compile-time direction (wave-uniform up)
template<bool DESC>
__device__ __forceinline__ void tail_net(float v[VPT]) {
#pragma unroll
  for (int j = 16; j > 0; j >>= 1) {
#pragma unroll
    for (int r = 0; r < VPT; r++) {
      if (!(r & j)) {
        float a = v[r], b = v[r | j];
        if constexpr (!DESC) { v[r] = fminf(a, b); v[r | j] = fmaxf(a, b); }
        else                 { v[r] = fmaxf(a, b); v[r | j] = fminf(a, b); }
      }
    }
  }
}

// ladder for merges a=6..10: up = lane bit (A-5) -> keepmasks compile-time
template<int A, int MTOP>
__device__ __forceinline__ void ladder_const(float v[VPT], int tid) {
  constexpr unsigned long long B = km0(1 << (A - 5));
  if constexpr (MTOP >= 32) stage_m<32>(v, tid, ~(B ^ km0(32)));
  if constexpr (MTOP >= 16) stage_m<16>(v, tid, ~(B ^ km0(16)));
  if constexpr (MTOP >= 8)  stage_m<8>(v, tid, ~(B ^ km0(8)));
  if constexpr (MTOP >= 4)  stage_m<4>(v, tid, ~(B ^ km0(4)));
  if constexpr (MTOP >= 2)  stage_m<2>(v, tid, ~(B ^ km0(2)));
  if constexpr (MTOP >= 1)  stage_m<1>(v, tid, ~(B ^ km0(1)));
  tail_inreg(v, (tid & (1 << (A - 5))) == 0);
}

// ladder for merges a>=11: up wave-uniform -> readfirstlane-uniform masks
template<int MTOP>
__device__ __forceinline__ void ladder_uni(float v[VPT], int tid, bool up) {
  if constexpr (MTOP >= 32) stage_m<32>(v, tid, uni64(up ? km0(32) : ~km0(32)));
  if constexpr (MTOP >= 16) stage_m<16>(v, tid, uni64(up ? km0(16) : ~km0(16)));
  if constexpr (MTOP >= 8)  stage_m<8>(v, tid, uni64(up ? km0(8) : ~km0(8)));
  if constexpr (MTOP >= 4)  stage_m<4>(v, tid, uni64(up ? km0(4) : ~km0(4)));
  if constexpr (MTOP >= 2)  stage_m<2>(v, tid, uni64(up ? km0(2) : ~km0(2)));
  if constexpr (MTOP >= 1)  stage_m<1>(v, tid, uni64(up ? km0(1) : ~km0(1)));
  if (up) tail_net<false>(v); else tail_net<true>(v);
}

// Wave-crossing exchange stage (xor-mask m>=64 on tid), element-wise,
// SPLIT through the 64KB buffer in two 16-reg rounds. Column layout
// s[r*NT+tid]: conflict-free. keepMin wave-uniform (tid bits >=6) ->
// uniform branch, 1 VALU per CE.
template<int NT>
__device__ __forceinline__ void stage_exch(float v[VPT], float* s, int tid,
                                           int m, bool up) {
  const bool keepMin = (up == ((tid & m) == 0));   // wave-uniform
  const int pt = tid ^ m;
#pragma unroll
  for (int h = 0; h < 2; h++) {
    __syncthreads();                  // prior users of s must finish
#pragma unroll
    for (int r = 0; r < VPT / 2; r++)
      s[r * NT + tid] = v[h * (VPT / 2) + r];
    __syncthreads();
    if (keepMin) {
#pragma unroll
      for (int r = 0; r < VPT / 2; r++)
        v[h * (VPT / 2) + r] = fminf(v[h * (VPT / 2) + r], s[r * NT + pt]);
    } else {
#pragma unroll
      for (int r = 0; r < VPT / 2; r++)
        v[h * (VPT / 2) + r] = fmaxf(v[h * (VPT / 2) + r], s[r * NT + pt]);
    }
  }
}

// in-register merges a=1..4 (k=2..16), compile-time directions
__device__ __forceinline__ void low_merges_inreg(float v[VPT]) {
#pragma unroll
  for (int k = 2; k <= 16; k <<= 1) {
#pragma unroll
    for (int j = k >> 1; j > 0; j >>= 1) {
#pragma unroll
      for (int r = 0; r < VPT; r++)
        if (!(r & j)) ce(v[r], v[r | j], (r & k) == 0);
    }
  }
}

// ---- full 32K distributed bitonic sort, 1024 threads ----
__device__ __forceinline__ void sort_dist(float v[VPT], float* s, int tid) {
  low_merges_inreg(v);
  tail_inreg(v, (tid & 1) == 0);          // a=5 (lane-varying dir)
  ladder_const<6, 1>(v, tid);
  ladder_const<7, 2>(v, tid);
  ladder_const<8, 4>(v, tid);
  ladder_const<9, 8>(v, tid);
  ladder_const<10, 16>(v, tid);
  ladder_uni<32>(v, tid, (tid & 64) == 0);        // a=11 (up = bit6, uniform)
  stage_exch<T1024>(v, s, tid, 64, (tid & 128) == 0);
  ladder_uni<32>(v, tid, (tid & 128) == 0);       // a=12
  {
    const bool u = (tid & 256) == 0;
    stage_exch<T1024>(v, s, tid, 128, u);
    stage_exch<T1024>(v, s, tid, 64, u);
  }
  ladder_uni<32>(v, tid, (tid & 256) == 0);       // a=13
  {
    const bool u = (tid & 512) == 0;
    stage_exch<T1024>(v, s, tid, 256, u);
    stage_exch<T1024>(v, s, tid, 128, u);
    stage_exch<T1024>(v, s, tid, 64, u);
  }
  ladder_uni<32>(v, tid, (tid & 512) == 0);       // a=14
  stage_exch<T1024>(v, s, tid, 512, true);
  stage_exch<T1024>(v, s, tid, 256, true);
  stage_exch<T1024>(v, s, tid, 128, true);
  stage_exch<T1024>(v, s, tid, 64, true);
  ladder_uni<32>(v, tid, true);                   // a=15
}

__device__ __forceinline__ void project_slice(const float4* base, float t0, float t1,
                                              int tid, float v[VPT]) {
#pragma unroll
  for (int q = 0; q < VPT / 2; q++) {
    float4 u = base[tid * (VPT / 2) + q];
    v[2 * q]     = fmaf(u.x, t0, u.y * t1);
    v[2 * q + 1] = fmaf(u.z, t0, u.w * t1);
  }
}

// ==================== fused single-dispatch kernel ====================

extern "C" __global__ void __launch_bounds__(T1024, 8)
swd_fused(const float* __restrict__ x, const float* __restrict__ y,
          const float* __restrict__ proj, float* __restrict__ w2,
          unsigned* __restrict__ flags, unsigned* __restrict__ ticket,
          float* __restrict__ xs) {
  extern __shared__ float s[];
  __shared__ unsigned su;
  __shared__ float wsum[T1024 / 64];
  const int tid = threadIdx.x;
  if (tid == 0) su = atomicAdd(ticket, 1u);
  __syncthreads();
  const unsigned unit = su;

  if (unit < (unsigned)SLICES) {
    // ---- sort X slice, stage, release flag ----
    const int slice = (int)unit;
    const int p  = slice % Pp;
    const int bc = slice / Pp;
    const float t0 = proj[2 * p];
    const float t1 = proj[2 * p + 1];
    float v[VPT];
    project_slice((const float4*)(x + (size_t)bc * Nn * 2), t0, t1, tid, v);
    sort_dist(v, s, tid);
    float4* o = (float4*)(xs + (size_t)slice * Nn + tid * VPT);
#pragma unroll
    for (int q = 0; q < VPT / 4; q++)
      o[q] = make_float4(v[4 * q], v[4 * q + 1], v[4 * q + 2], v[4 * q + 3]);
    __syncthreads();                        // all stores issued & drained
    if (tid == 0) {
      __threadfence();                      // device-scope release
      atomicOr(&flags[slice >> 5], 1u << (slice & 31));
    }
  } else {
    // ---- sort Y slice, acquire X, diff, reduce ----
    const int slice = (int)unit - SLICES;
    const int p  = slice % Pp;
    const int bc = slice / Pp;
    const float t0 = proj[2 * p];
    const float t1 = proj[2 * p + 1];
    float v[VPT];
    project_slice((const float4*)(y + (size_t)bc * Nn * 2), t0, t1, tid, v);
    sort_dist(v, s, tid);

    // acquire: partner's ticket was >=1600 pops earlier -> resident or done;
    // our own ~400us sort already covered it, spin is a safety net only.
    if (tid == 0) {
      while (((atomicAdd(&flags[slice >> 5], 0u) >> (slice & 31)) & 1u) == 0u) {}
      __threadfence();                      // device-scope acquire
    }
    __syncthreads();

    const float4* xr = (const float4*)(xs + (size_t)slice * Nn + tid * VPT);
    float acc = 0.f;
#pragma unroll
    for (int q = 0; q < VPT / 4; q++) {
      float4 u = xr[q];
      float d0 = u.x - v[4 * q];
      float d1 = u.y - v[4 * q + 1];
      float d2 = u.z - v[4 * q + 2];
      float d3 = u.w - v[4 * q + 3];
      acc = fmaf(d0, d0, acc);
      acc = fmaf(d1, d1, acc);
      acc = fmaf(d2, d2, acc);
      acc = fmaf(d3, d3, acc);
    }
#pragma unroll
    for (int off = 32; off > 0; off >>= 1)
      acc += __shfl_down(acc, off, 64);
    if ((tid & 63) == 0) wsum[tid >> 6] = acc;
    __syncthreads();
    if (tid == 0) {
      float t = 0.f;
#pragma unroll
      for (int w = 0; w < T1024 / 64; w++) t += wsum[w];
      w2[slice] = t * (1.0f / Nn);
    }
  }
}

extern "C" __global__ void swd_reset(unsigned* __restrict__ flags,
                                     unsigned* __restrict__ ticket) {
  int t = threadIdx.x;
  if (t < FLAG_WORDS) flags[t] = 0u;
  if (t == 63) *ticket = 0u;
}

// ==================== legacy kernels (fallback for tiny ws) ====================

extern "C" __global__ void __launch_bounds__(T1024, 8)
swd_sortx(const float* __restrict__ x, const float* __restrict__ proj,
          float* __restrict__ xs, int slice_base) {
  extern __shared__ float s[];
  const int slice = slice_base + blockIdx.x;
  const int p  = slice % Pp;
  const int bc = slice / Pp;
  const int tid = threadIdx.x;
  const float t0 = proj[2 * p];
  const float t1 = proj[2 * p + 1];
  float v[VPT];
  project_slice((const float4*)(x + (size_t)bc * Nn * 2), t0, t1, tid, v);
  sort_dist(v, s, tid);
  float4* o = (float4*)(xs + (size_t)blockIdx.x * Nn + tid * VPT);
#pragma unroll
  for (int q = 0; q < VPT / 4; q++)
    o[q] = make_float4(v[4 * q], v[4 * q + 1], v[4 * q + 2], v[4 * q + 3]);
}

extern "C" __global__ void __launch_bounds__(T1024, 8)
swd_sorty(const float* __restrict__ y, const float* __restrict__ proj,
          const float* __restrict__ xs, float* __restrict__ w2, int slice_base) {
  extern __shared__ float s[];
  __shared__ float wsum[T1024 / 64];
  const int slice = slice_base + blockIdx.x;
  const int p  = slice % Pp;
  const int bc = slice / Pp;
  const int tid = threadIdx.x;
  const float t0 = proj[2 * p];
  const float t1 = proj[2 * p + 1];
  float v[VPT];
  project_slice((const float4*)(y + (size_t)bc * Nn * 2), t0, t1, tid, v);
  sort_dist(v, s, tid);

  const float4* xr = (const float4*)(xs + (size_t)blockIdx.x * Nn + tid * VPT);
  float acc = 0.f;
#pragma unroll
  for (int q = 0; q < VPT / 4; q++) {
    float4 u = xr[q];
    float d0 = u.x - v[4 * q];
    float d1 = u.y - v[4 * q + 1];
    float d2 = u.z - v[4 * q + 2];
    float d3 = u.w - v[4 * q + 3];
    acc = fmaf(d0, d0, acc);
    acc = fmaf(d1, d1, acc);
    acc = fmaf(d2, d2, acc);
    acc = fmaf(d3, d3, acc);
  }
#pragma unroll
  for (int off = 32; off > 0; off >>= 1)
    acc += __shfl_down(acc, off, 64);
  if ((tid & 63) == 0) wsum[tid >> 6] = acc;
  __syncthreads();
  if (tid == 0) {
    float t = 0.f;
#pragma unroll
    for (int w = 0; w < T1024 / 64; w++) t += wsum[w];
    w2[slice] = t * (1.0f / Nn);
  }
}

extern "C" __global__ void swd_final(const float* __restrict__ w2,
                                     float* __restrict__ out) {
  __shared__ float sred[Bb * Cc];
  int t = threadIdx.x;
  if (t < Bb * Cc) {
    float sum = 0.f;
    for (int p = 0; p < Pp; p++) sum += w2[t * Pp + p];
    sred[t] = sqrtf(sum * (1.0f / Pp));
  }
  __syncthreads();
  if (t == 0) {
    float a = 0.f;
    for (int i = 0; i < Bb * Cc; i++) a += sred[i];
    out[0] = a * (1.0f / (Bb * Cc));
  }
}

extern "C" void kernel_launch(void* const* d_in, const int* in_sizes, int n_in,
                              void* d_out, int out_size, void* d_ws, size_t ws_size,
                              hipStream_t stream) {
  const float* x    = (const float*)d_in[0];
  const float* y    = (const float*)d_in[1];
  const float* proj = (const float*)d_in[2];
  float* w2       = (float*)d_ws;                  // 6400 B
  unsigned* flags = (unsigned*)((char*)d_ws + FLAGS_OFF);   // 200 B
  unsigned* tick  = (unsigned*)((char*)d_ws + TICKET_OFF);  // 4 B
  float* xs       = (float*)((char*)d_ws + W2_BYTES);       // sorted-X staging
  float* out      = (float*)d_out;

  const size_t lds_full = (size_t)LDS_FLOATS_FULL * sizeof(float);  // 64 KB
  (void)hipFuncSetAttribute((const void*)swd_fused,
                            hipFuncAttributeMaxDynamicSharedMemorySize, (int)lds_full);
  (void)hipFuncSetAttribute((const void*)swd_sortx,
                            hipFuncAttributeMaxDynamicSharedMemorySize, (int)lds_full);
  (void)hipFuncSetAttribute((const void*)swd_sorty,
                            hipFuncAttributeMaxDynamicSharedMemorySize, (int)lds_full);

  const size_t avail = ws_size > W2_BYTES ? ws_size - W2_BYTES : 0;
  const size_t slice_bytes = (size_t)Nn * sizeof(float);            // 128 KB

  if (avail >= (size_t)SLICES * slice_bytes) {
    // ---- single fused dispatch: 3200 ticket-ordered units ----
    hipLaunchKernelGGL(swd_reset, dim3(1), dim3(64), 0, stream, flags, tick);
    hipLaunchKernelGGL(swd_fused, dim3(SLICES * 2), dim3(T1024), lds_full,
                       stream, x, y, proj, w2, flags, tick, xs);
  } else {
    // ---- legacy chunked two-kernel path ----
    int chunk = (int)(avail / slice_bytes);
    if (chunk > SLICES) chunk = SLICES;
    if (chunk < 1) chunk = 1;
    for (int base = 0; base < SLICES; base += chunk) {
      int n = SLICES - base < chunk ? SLICES - base : chunk;
      hipLaunchKernelGGL(swd_sortx, dim3(n), dim3(T1024), lds_full, stream,
                         x, proj, xs, base);
      hipLaunchKernelGGL(swd_sorty, dim3(n), dim3(T1024), lds_full, stream,
                         y, proj, xs, w2, base);
    }
  }
  hipLaunchKernelGGL(swd_final, dim3(1), dim3(64), 0, stream, w2, out);
}

// Round 9
// 990.537 us; speedup vs baseline: 1.0088x; 1.0088x over previous
//
#include <hip/hip_runtime.h>
#include <math.h>

// Sliced Wasserstein-2: for each (b,c,p): W2^2 = mean_i (sort(X@theta_p) - sort(Y@theta_p))^2
// loss = mean_{b,c} sqrt(mean_p W2^2)
//
// R25 = R22 (fused ticket-queue single dispatch, best-known 832us) + the two
// SAFE pure-C++ VALU cuts from the R24 bundle, with the inline-asm mask-XOR
// CE REMOVED (R24 post-mortem: asm operand-tying + vcc clobber x1440 caused
// ~630MB of scratch spill traffic per dispatch, WRITE 256->780MB, -20% perf).
//  1) exch-stage CEs: keepMin is wave-uniform (tid bits >=6) -> uniform
//     branch, plain fminf OR fmaxf = 1 VALU/CE (sel_ce was 2).
//  2) tails for merges a=11..15: direction wave-uniform -> specialized
//     min/max networks (template), no sign-flip XOR wrapper (-64 XOR/tail).
// Cross-lane ladders keep R22's sel_ce (lane-varying keep: cmp+cndmask is
// optimal; two asm attempts regressed). Numerics: only +-0 bit patterns can
// differ vs R22; squared diffs identical -> absmax 0.

namespace {
constexpr int Bb = 8, Cc = 4, Nn = 32768, Pp = 50;
constexpr int T1024 = 1024;
constexpr int VPT = 32;                    // values per thread
constexpr int SLICES = Bb * Cc * Pp;       // 1600
constexpr int FLAG_WORDS = (SLICES + 31) / 32;  // 50
constexpr size_t W2_BYTES = 8192;          // w2[1600] + flags + ticket
constexpr size_t FLAGS_OFF = 6400;         // after w2 floats
constexpr size_t TICKET_OFF = 6656;
constexpr int LDS_FLOATS_FULL = Nn / 2;    // 16384 floats = 64 KB
}

__device__ __forceinline__ void ce(float& a, float& b, bool up) {
  float lo = fminf(a, b);
  float hi = fmaxf(a, b);
  a = up ? lo : hi;
  b = up ? hi : lo;
}

// 2-VALU compare-select CE: keepMin ? min(v,o) : max(v,o); ties resolve
// consistently on both partners (multiset preserved).
__device__ __forceinline__ float sel_ce(float v, float o, bool keepMin) {
  return ((o < v) != keepMin) ? v : o;
}

// DPP lane move with compile-time control word.
// 0xB1 = quad_perm(1,0,3,2) = xor1; 0x4E = quad_perm(2,3,0,1) = xor2;
// 0x128 = row_ror:8 = xor8 on each 16-lane row.
template<int CTRL>
__device__ __forceinline__ float dpp_move(float x) {
  int i = __builtin_amdgcn_update_dpp(0, __float_as_int(x), CTRL, 0xF, 0xF, true);
  return __int_as_float(i);
}

// cross-lane CE stage with xor-mask M (M=1,2,8 via DPP; M=4,16,32 bpermute)
template<int M>
__device__ __forceinline__ void stage_xlane(float v[VPT], int tid, bool up) {
  const bool keepMin = (up == ((tid & M) == 0));
  if constexpr (M == 1 || M == 2 || M == 8) {
    constexpr int ctrl = (M == 1) ? 0xB1 : (M == 2) ? 0x4E : 0x128;
#pragma unroll
    for (int r = 0; r < VPT; r++) {
      float o = dpp_move<ctrl>(v[r]);
      v[r] = sel_ce(v[r], o, keepMin);
    }
  } else {
    const int addr = (((tid & 63) ^ M) << 2);
#pragma unroll
    for (int r = 0; r < VPT; r++) {
      float o = __int_as_float(
          __builtin_amdgcn_ds_bpermute(addr, __float_as_int(v[r])));
      v[r] = sel_ce(v[r], o, keepMin);
    }
  }
}

// 5-stage in-register network, sign-flip direction (lane-varying up)
__device__ __forceinline__ void tail_inreg(float v[VPT], bool up) {
  const unsigned flip = up ? 0u : 0x80000000u;
#pragma unroll
  for (int r = 0; r < VPT; r++)
    v[r] = __int_as_float(__float_as_int(v[r]) ^ flip);
#pragma unroll
  for (int j = 16; j > 0; j >>= 1) {
#pragma unroll
    for (int r = 0; r < VPT; r++) {
      if (!(r & j)) {
        float a = v[r], b = v[r | j];
        v[r] = fminf(a, b);
        v[r | j] = fmaxf(a, b);
      }
    }
  }
#pragma unroll
  for (int r = 0; r < VPT; r++)
    v[r] = __int_as_float(__float_as_int(v[r]) ^ flip);
}

// 5-stage in-register network, compile-time direction (wave-uniform up)
template<bool DESC>
__device__ __forceinline__ void tail_net(float v[VPT]) {
#pragma unroll
  for (int j = 16; j > 0; j >>= 1) {
#pragma unroll
    for (int r = 0; r < VPT; r++) {
      if (!(r & j)) {
        float a = v[r], b = v[r | j];
        if constexpr (!DESC) { v[r] = fminf(a, b); v[r | j] = fmaxf(a, b); }
        else                 { v[r] = fmaxf(a, b); v[r | j] = fminf(a, b); }
      }
    }
  }
}

// wave ladder for a=6..10 (lane-varying direction bit): R22 code path
template<int A, int MTOP>
__device__ __forceinline__ void wave_stages_and_tail(float v[VPT], int tid) {
  const bool up = ((tid & (1 << (A - 5))) == 0);
  if constexpr (MTOP >= 32) stage_xlane<32>(v, tid, up);
  if constexpr (MTOP >= 16) stage_xlane<16>(v, tid, up);
  if constexpr (MTOP >= 8)  stage_xlane<8>(v, tid, up);
  if constexpr (MTOP >= 4)  stage_xlane<4>(v, tid, up);
  if constexpr (MTOP >= 2)  stage_xlane<2>(v, tid, up);
  if constexpr (MTOP >= 1)  stage_xlane<1>(v, tid, up);
  tail_inreg(v, up);
}

// wave ladder for a>=11 (wave-uniform direction): branch-specialized tail
__device__ __forceinline__ void wave_ladder_uni(float v[VPT], int tid, bool up) {
  stage_xlane<32>(v, tid, up);
  stage_xlane<16>(v, tid, up);
  stage_xlane<8>(v, tid, up);
  stage_xlane<4>(v, tid, up);
  stage_xlane<2>(v, tid, up);
  stage_xlane<1>(v, tid, up);
  if (up) tail_net<false>(v); else tail_net<true>(v);
}

// Wave-crossing exchange stage (xor-mask m>=64 on tid), element-wise,
// SPLIT through the 64KB buffer in two 16-reg rounds. Column layout
// s[r*NT+tid]: conflict-free. keepMin wave-uniform (tid bits >=6) ->
// uniform branch, 1 VALU per CE.
template<int NT>
__device__ __forceinline__ void stage_exch(float v[VPT], float* s, int tid,
                                           int m, bool up) {
  const bool keepMin = (up == ((tid & m) == 0));   // wave-uniform
  const int pt = tid ^ m;
#pragma unroll
  for (int h = 0; h < 2; h++) {
    __syncthreads();                  // prior users of s must finish
#pragma unroll
    for (int r = 0; r < VPT / 2; r++)
      s[r * NT + tid] = v[h * (VPT / 2) + r];
    __syncthreads();
    if (keepMin) {
#pragma unroll
      for (int r = 0; r < VPT / 2; r++)
        v[h * (VPT / 2) + r] = fminf(v[h * (VPT / 2) + r], s[r * NT + pt]);
    } else {
#pragma unroll
      for (int r = 0; r < VPT / 2; r++)
        v[h * (VPT / 2) + r] = fmaxf(v[h * (VPT / 2) + r], s[r * NT + pt]);
    }
  }
}

// in-register merges a=1..4 (k=2..16), compile-time directions
__device__ __forceinline__ void low_merges_inreg(float v[VPT]) {
#pragma unroll
  for (int k = 2; k <= 16; k <<= 1) {
#pragma unroll
    for (int j = k >> 1; j > 0; j >>= 1) {
#pragma unroll
      for (int r = 0; r < VPT; r++)
        if (!(r & j)) ce(v[r], v[r | j], (r & k) == 0);
    }
  }
}

// ---- full 32K distributed bitonic sort, 1024 threads ----
__device__ __forceinline__ void sort_dist(float v[VPT], float* s, int tid) {
  low_merges_inreg(v);
  tail_inreg(v, (tid & 1) == 0);          // a=5 (lane-varying dir)
  wave_stages_and_tail<6, 1>(v, tid);
  wave_stages_and_tail<7, 2>(v, tid);
  wave_stages_and_tail<8, 4>(v, tid);
  wave_stages_and_tail<9, 8>(v, tid);
  wave_stages_and_tail<10, 16>(v, tid);
  wave_ladder_uni(v, tid, (tid & 64) == 0);       // a=11 (up = bit6, uniform)
  stage_exch<T1024>(v, s, tid, 64, (tid & 128) == 0);
  wave_ladder_uni(v, tid, (tid & 128) == 0);      // a=12
  {
    const bool u = (tid & 256) == 0;
    stage_exch<T1024>(v, s, tid, 128, u);
    stage_exch<T1024>(v, s, tid, 64, u);
  }
  wave_ladder_uni(v, tid, (tid & 256) == 0);      // a=13
  {
    const bool u = (tid & 512) == 0;
    stage_exch<T1024>(v, s, tid, 256, u);
    stage_exch<T1024>(v, s, tid, 128, u);
    stage_exch<T1024>(v, s, tid, 64, u);
  }
  wave_ladder_uni(v, tid, (tid & 512) == 0);      // a=14
  stage_exch<T1024>(v, s, tid, 512, true);
  stage_exch<T1024>(v, s, tid, 256, true);
  stage_exch<T1024>(v, s, tid, 128, true);
  stage_exch<T1024>(v, s, tid, 64, true);
  wave_ladder_uni(v, tid, true);                  // a=15
}

__device__ __forceinline__ void project_slice(const float4* base, float t0, float t1,
                                              int tid, float v[VPT]) {
#pragma unroll
  for (int q = 0; q < VPT / 2; q++) {
    float4 u = base[tid * (VPT / 2) + q];
    v[2 * q]     = fmaf(u.x, t0, u.y * t1);
    v[2 * q + 1] = fmaf(u.z, t0, u.w * t1);
  }
}

// ==================== fused single-dispatch kernel ====================

extern "C" __global__ void __launch_bounds__(T1024, 8)
swd_fused(const float* __restrict__ x, const float* __restrict__ y,
          const float* __restrict__ proj, float* __restrict__ w2,
          unsigned* __restrict__ flags, unsigned* __restrict__ ticket,
          float* __restrict__ xs) {
  extern __shared__ float s[];
  __shared__ unsigned su;
  __shared__ float wsum[T1024 / 64];
  const int tid = threadIdx.x;
  if (tid == 0) su = atomicAdd(ticket, 1u);
  __syncthreads();
  const unsigned unit = su;

  if (unit < (unsigned)SLICES) {
    // ---- sort X slice, stage, release flag ----
    const int slice = (int)unit;
    const int p  = slice % Pp;
    const int bc = slice / Pp;
    const float t0 = proj[2 * p];
    const float t1 = proj[2 * p + 1];
    float v[VPT];
    project_slice((const float4*)(x + (size_t)bc * Nn * 2), t0, t1, tid, v);
    sort_dist(v, s, tid);
    float4* o = (float4*)(xs + (size_t)slice * Nn + tid * VPT);
#pragma unroll
    for (int q = 0; q < VPT / 4; q++)
      o[q] = make_float4(v[4 * q], v[4 * q + 1], v[4 * q + 2], v[4 * q + 3]);
    __syncthreads();                        // all stores issued & drained
    if (tid == 0) {
      __threadfence();                      // device-scope release
      atomicOr(&flags[slice >> 5], 1u << (slice & 31));
    }
  } else {
    // ---- sort Y slice, acquire X, diff, reduce ----
    const int slice = (int)unit - SLICES;
    const int p  = slice % Pp;
    const int bc = slice / Pp;
    const float t0 = proj[2 * p];
    const float t1 = proj[2 * p + 1];
    float v[VPT];
    project_slice((const float4*)(y + (size_t)bc * Nn * 2), t0, t1, tid, v);
    sort_dist(v, s, tid);

    // acquire: partner's ticket was >=1600 pops earlier -> resident or done;
    // our own ~400us sort already covered it, spin is a safety net only.
    if (tid == 0) {
      while (((atomicAdd(&flags[slice >> 5], 0u) >> (slice & 31)) & 1u) == 0u) {}
      __threadfence();                      // device-scope acquire
    }
    __syncthreads();

    const float4* xr = (const float4*)(xs + (size_t)slice * Nn + tid * VPT);
    float acc = 0.f;
#pragma unroll
    for (int q = 0; q < VPT / 4; q++) {
      float4 u = xr[q];
      float d0 = u.x - v[4 * q];
      float d1 = u.y - v[4 * q + 1];
      float d2 = u.z - v[4 * q + 2];
      float d3 = u.w - v[4 * q + 3];
      acc = fmaf(d0, d0, acc);
      acc = fmaf(d1, d1, acc);
      acc = fmaf(d2, d2, acc);
      acc = fmaf(d3, d3, acc);
    }
#pragma unroll
    for (int off = 32; off > 0; off >>= 1)
      acc += __shfl_down(acc, off, 64);
    if ((tid & 63) == 0) wsum[tid >> 6] = acc;
    __syncthreads();
    if (tid == 0) {
      float t = 0.f;
#pragma unroll
      for (int w = 0; w < T1024 / 64; w++) t += wsum[w];
      w2[slice] = t * (1.0f / Nn);
    }
  }
}

extern "C" __global__ void swd_reset(unsigned* __restrict__ flags,
                                     unsigned* __restrict__ ticket) {
  int t = threadIdx.x;
  if (t < FLAG_WORDS) flags[t] = 0u;
  if (t == 63) *ticket = 0u;
}

// ==================== legacy kernels (fallback for tiny ws) ====================

extern "C" __global__ void __launch_bounds__(T1024, 8)
swd_sortx(const float* __restrict__ x, const float* __restrict__ proj,
          float* __restrict__ xs, int slice_base) {
  extern __shared__ float s[];
  const int slice = slice_base + blockIdx.x;
  const int p  = slice % Pp;
  const int bc = slice / Pp;
  const int tid = threadIdx.x;
  const float t0 = proj[2 * p];
  const float t1 = proj[2 * p + 1];
  float v[VPT];
  project_slice((const float4*)(x + (size_t)bc * Nn * 2), t0, t1, tid, v);
  sort_dist(v, s, tid);
  float4* o = (float4*)(xs + (size_t)blockIdx.x * Nn + tid * VPT);
#pragma unroll
  for (int q = 0; q < VPT / 4; q++)
    o[q] = make_float4(v[4 * q], v[4 * q + 1], v[4 * q + 2], v[4 * q + 3]);
}

extern "C" __global__ void __launch_bounds__(T1024, 8)
swd_sorty(const float* __restrict__ y, const float* __restrict__ proj,
          const float* __restrict__ xs, float* __restrict__ w2, int slice_base) {
  extern __shared__ float s[];
  __shared__ float wsum[T1024 / 64];
  const int slice = slice_base + blockIdx.x;
  const int p  = slice % Pp;
  const int bc = slice / Pp;
  const int tid = threadIdx.x;
  const float t0 = proj[2 * p];
  const float t1 = proj[2 * p + 1];
  float v[VPT];
  project_slice((const float4*)(y + (size_t)bc * Nn * 2), t0, t1, tid, v);
  sort_dist(v, s, tid);

  const float4* xr = (const float4*)(xs + (size_t)blockIdx.x * Nn + tid * VPT);
  float acc = 0.f;
#pragma unroll
  for (int q = 0; q < VPT / 4; q++) {
    float4 u = xr[q];
    float d0 = u.x - v[4 * q];
    float d1 = u.y - v[4 * q + 1];
    float d2 = u.z - v[4 * q + 2];
    float d3 = u.w - v[4 * q + 3];
    acc = fmaf(d0, d0, acc);
    acc = fmaf(d1, d1, acc);
    acc = fmaf(d2, d2, acc);
    acc = fmaf(d3, d3, acc);
  }
#pragma unroll
  for (int off = 32; off > 0; off >>= 1)
    acc += __shfl_down(acc, off, 64);
  if ((tid & 63) == 0) wsum[tid >> 6] = acc;
  __syncthreads();
  if (tid == 0) {
    float t = 0.f;
#pragma unroll
    for (int w = 0; w < T1024 / 64; w++) t += wsum[w];
    w2[slice] = t * (1.0f / Nn);
  }
}

extern "C" __global__ void swd_final(const float* __restrict__ w2,
                                     float* __restrict__ out) {
  __shared__ float sred[Bb * Cc];
  int t = threadIdx.x;
  if (t < Bb * Cc) {
    float sum = 0.f;
    for (int p = 0; p < Pp; p++) sum += w2[t * Pp + p];
    sred[t] = sqrtf(sum * (1.0f / Pp));
  }
  __syncthreads();
  if (t == 0) {
    float a = 0.f;
    for (int i = 0; i < Bb * Cc; i++) a += sred[i];
    out[0] = a * (1.0f / (Bb * Cc));
  }
}

extern "C" void kernel_launch(void* const* d_in, const int* in_sizes, int n_in,
                              void* d_out, int out_size, void* d_ws, size_t ws_size,
                              hipStream_t stream) {
  const float* x    = (const float*)d_in[0];
  const float* y    = (const float*)d_in[1];
  const float* proj = (const float*)d_in[2];
  float* w2       = (float*)d_ws;                  // 6400 B
  unsigned* flags = (unsigned*)((char*)d_ws + FLAGS_OFF);   // 200 B
  unsigned* tick  = (unsigned*)((char*)d_ws + TICKET_OFF);  // 4 B
  float* xs       = (float*)((char*)d_ws + W2_BYTES);       // sorted-X staging
  float* out      = (float*)d_out;

  const size_t lds_full = (size_t)LDS_FLOATS_FULL * sizeof(float);  // 64 KB
  (void)hipFuncSetAttribute((const void*)swd_fused,
                            hipFuncAttributeMaxDynamicSharedMemorySize, (int)lds_full);
  (void)hipFuncSetAttribute((const void*)swd_sortx,
                            hipFuncAttributeMaxDynamicSharedMemorySize, (int)lds_full);
  (void)hipFuncSetAttribute((const void*)swd_sorty,
                            hipFuncAttributeMaxDynamicSharedMemorySize, (int)lds_full);

  const size_t avail = ws_size > W2_BYTES ? ws_size - W2_BYTES : 0;
  const size_t slice_bytes = (size_t)Nn * sizeof(float);            // 128 KB

  if (avail >= (size_t)SLICES * slice_bytes) {
    // ---- single fused dispatch: 3200 ticket-ordered units ----
    hipLaunchKernelGGL(swd_reset, dim3(1), dim3(64), 0, stream, flags, tick);
    hipLaunchKernelGGL(swd_fused, dim3(SLICES * 2), dim3(T1024), lds_full,
                       stream, x, y, proj, w2, flags, tick, xs);
  } else {
    // ---- legacy chunked two-kernel path ----
    int chunk = (int)(avail / slice_bytes);
    if (chunk > SLICES) chunk = SLICES;
    if (chunk < 1) chunk = 1;
    for (int base = 0; base < SLICES; base += chunk) {
      int n = SLICES - base < chunk ? SLICES - base : chunk;
      hipLaunchKernelGGL(swd_sortx, dim3(n), dim3(T1024), lds_full, stream,
                         x, proj, xs, base);
      hipLaunchKernelGGL(swd_sorty, dim3(n), dim3(T1024), lds_full, stream,
                         y, proj, xs, w2, base);
    }
  }
  hipLaunchKernelGGL(swd_final, dim3(1), dim3(64), 0, stream, w2, out);
}